// Round 2
// baseline (23.849 us; speedup 1.0000x reference)
//
#include <hip/hip_runtime.h>

#define HIDDEN 64
#define MASK_FILL -1e9f

// Fold W2/b2/Ws/bs into v[64] + c (scores = relu(ei@W1+b1)·v + c).
__global__ void precompute_vc(const float* __restrict__ W2,
                              const float* __restrict__ b2,
                              const float* __restrict__ Ws,
                              const float* __restrict__ bs,
                              float* __restrict__ vc) {
    int k = threadIdx.x;
    if (k < HIDDEN) {
        float acc = 0.f;
#pragma unroll
        for (int j = 0; j < HIDDEN; ++j)
            acc = fmaf(W2[k * HIDDEN + j], Ws[j], acc);
        vc[k] = acc;
    }
    if (k == 0) {
        float c = bs[0];
#pragma unroll
        for (int j = 0; j < HIDDEN; ++j)
            c = fmaf(b2[j], Ws[j], c);
        vc[HIDDEN] = c;
    }
}

__global__ __launch_bounds__(256) void edge_score_kernel(
    const float* __restrict__ x,                 // [N,1]
    const int* __restrict__ edge_index,          // [2,E] int32
    const float* __restrict__ edge_attr,         // [E,2]
    const int* __restrict__ edge_mask,           // [E] int32 (bool pushed as int)
    const float* __restrict__ W1,                // [4,64] row-major
    const float* __restrict__ b1,                // [64]
    const float* __restrict__ vc,                // [65] = v[64], c
    float* __restrict__ out, int E)
{
    int t = blockIdx.x * blockDim.x + threadIdx.x;
    int e = t * 4;
    if (e >= E) return;  // E % 4 == 0, so active threads have 4 full edges

    const int4 rows = *reinterpret_cast<const int4*>(edge_index + e);
    const int4 cols = *reinterpret_cast<const int4*>(edge_index + E + e);
    const float4 eaA = *reinterpret_cast<const float4*>(edge_attr + 2 * e);
    const float4 eaB = *reinterpret_cast<const float4*>(edge_attr + 2 * e + 4);
    const int4 mk    = *reinterpret_cast<const int4*>(edge_mask + e);

    // gather node features (x is 200KB -> L2-resident)
    const float xr0 = x[rows.x], xr1 = x[rows.y], xr2 = x[rows.z], xr3 = x[rows.w];
    const float xc0 = x[cols.x], xc1 = x[cols.y], xc2 = x[cols.z], xc3 = x[cols.w];

    float s0 = 0.f, s1 = 0.f, s2 = 0.f, s3 = 0.f;

#pragma unroll
    for (int k = 0; k < HIDDEN; ++k) {
        const float w0 = W1[k];
        const float w1 = W1[HIDDEN + k];
        const float w2 = W1[2 * HIDDEN + k];
        const float w3 = W1[3 * HIDDEN + k];
        const float bb = b1[k];
        const float vk = vc[k];

        float h0 = fmaf(xr0, w0, fmaf(xc0, w1, fmaf(eaA.x, w2, fmaf(eaA.y, w3, bb))));
        float h1 = fmaf(xr1, w0, fmaf(xc1, w1, fmaf(eaA.z, w2, fmaf(eaA.w, w3, bb))));
        float h2 = fmaf(xr2, w0, fmaf(xc2, w1, fmaf(eaB.x, w2, fmaf(eaB.y, w3, bb))));
        float h3 = fmaf(xr3, w0, fmaf(xc3, w1, fmaf(eaB.z, w2, fmaf(eaB.w, w3, bb))));
        h0 = fmaxf(h0, 0.f); h1 = fmaxf(h1, 0.f);
        h2 = fmaxf(h2, 0.f); h3 = fmaxf(h3, 0.f);
        s0 = fmaf(h0, vk, s0); s1 = fmaf(h1, vk, s1);
        s2 = fmaf(h2, vk, s2); s3 = fmaf(h3, vk, s3);
    }

    const float c = vc[HIDDEN];
    float4 res;
    res.x = mk.x ? (s0 + c) : MASK_FILL;
    res.y = mk.y ? (s1 + c) : MASK_FILL;
    res.z = mk.z ? (s2 + c) : MASK_FILL;
    res.w = mk.w ? (s3 + c) : MASK_FILL;
    *reinterpret_cast<float4*>(out + e) = res;
}

extern "C" void kernel_launch(void* const* d_in, const int* in_sizes, int n_in,
                              void* d_out, int out_size, void* d_ws, size_t ws_size,
                              hipStream_t stream) {
    const float* x          = (const float*)d_in[0];
    const int*   edge_index = (const int*)d_in[1];   // int64 request downcast -> int32
    const float* edge_attr  = (const float*)d_in[2];
    const int*   edge_mask  = (const int*)d_in[3];   // bool pushed as int32
    const float* W1 = (const float*)d_in[4];
    const float* b1 = (const float*)d_in[5];
    const float* W2 = (const float*)d_in[6];
    const float* b2 = (const float*)d_in[7];
    const float* Ws = (const float*)d_in[8];
    const float* bs = (const float*)d_in[9];
    float* out = (float*)d_out;
    float* vc  = (float*)d_ws;  // 65 floats

    const int E = out_size;  // 1,000,000

    precompute_vc<<<1, 64, 0, stream>>>(W2, b2, Ws, bs, vc);

    const int threads = 256;
    const int work = (E + 3) / 4;
    const int blocks = (work + threads - 1) / threads;
    edge_score_kernel<<<blocks, threads, 0, stream>>>(
        x, edge_index, edge_attr, edge_mask, W1, b1, vc, out, E);
}